// Round 1
// baseline (1071.657 us; speedup 1.0000x reference)
//
#include <hip/hip_runtime.h>

typedef unsigned short u16;

#define NT   16384   // B*T
#define CDIM 256
#define LAYERS 6

using bf16x8 = __attribute__((ext_vector_type(8))) __bf16;
using f32x4  = __attribute__((ext_vector_type(4))) float;

__device__ __forceinline__ u16 f2bf(float x){
  unsigned u = __float_as_uint(x);
  u += 0x7fffu + ((u >> 16) & 1u);
  return (u16)(u >> 16);
}

union BF8 { u16 u[8]; bf16x8 v; uint4 q; };

__device__ __forceinline__ void cvt8(const float4& a, const float4& b, BF8& p){
  p.u[0]=f2bf(a.x); p.u[1]=f2bf(a.y); p.u[2]=f2bf(a.z); p.u[3]=f2bf(a.w);
  p.u[4]=f2bf(b.x); p.u[5]=f2bf(b.y); p.u[6]=f2bf(b.z); p.u[7]=f2bf(b.w);
}

// ---------------------------------------------------------------------------
// Weight transpose+convert: src fp32 [K=256][N] -> dst bf16 [Npad][256]
// z in [0,36): 6 arrays x 6 layers (Wq,Wk,Wv,Wo,W1,W2), N=Npad=256.
// z==36: Wlm [256][96] -> [128][256], rows 96..127 zeroed.
// ---------------------------------------------------------------------------
__global__ __launch_bounds__(256) void wconv_k(
    const float* __restrict__ Wq, const float* __restrict__ Wk,
    const float* __restrict__ Wv, const float* __restrict__ Wo,
    const float* __restrict__ W1, const float* __restrict__ W2,
    const float* __restrict__ Wlm, u16* __restrict__ WT)
{
  __shared__ float tile[64][65];
  const int z = blockIdx.z;
  const float* src; int N, Npad;
  if (z < 36){
    const float* arr[6] = {Wq, Wk, Wv, Wo, W1, W2};
    src = arr[z / 6] + (size_t)(z % 6) * 65536;
    N = 256; Npad = 256;
  } else {
    src = Wlm; N = 96; Npad = 128;
  }
  const int n0 = blockIdx.y * 64, k0 = blockIdx.x * 64;
  if (n0 >= Npad) return;
  u16* dst = WT + (size_t)z * 65536;
  const int c = threadIdx.x & 63, r0 = threadIdx.x >> 6;
  #pragma unroll
  for (int i = 0; i < 16; ++i){
    const int r = r0 + i * 4;
    tile[r][c] = (n0 + c < N) ? src[(size_t)(k0 + r) * N + n0 + c] : 0.f;
  }
  __syncthreads();
  #pragma unroll
  for (int i = 0; i < 16; ++i){
    const int cp = r0 + i * 4;
    dst[(size_t)(n0 + cp) * CDIM + k0 + c] = f2bf(tile[c][cp]);
  }
}

// ---------------------------------------------------------------------------
// Embedding: X[r][c] = tok[idx[r]][c] + pos[r%256][c]
// ---------------------------------------------------------------------------
__global__ __launch_bounds__(256) void embed_k(
    const int* __restrict__ idx, const float* __restrict__ tok,
    const float* __restrict__ pos, float* __restrict__ X)
{
  const int r = blockIdx.x, c = threadIdx.x;
  X[(size_t)r * CDIM + c] =
      tok[(size_t)idx[r] * CDIM + c] + pos[(size_t)(r & 255) * CDIM + c];
}

// ---------------------------------------------------------------------------
// GEMM: out[M,N] = A[M,256](fp32) * W  where WT = bf16 [Npad][256] (row n = W[:,n])
// 128x128 tile, BK=64, 4 waves, 4x4 frags of mfma_f32_16x16x32_bf16.
// Epilogue: +bias, +residual, relu (template flags).
// ---------------------------------------------------------------------------
template<bool BIAS, bool RELU, bool RES>
__global__ __launch_bounds__(256) void gemm_k(
    const float* __restrict__ A, const u16* __restrict__ WT,
    const float* __restrict__ bias, const float* __restrict__ res,
    float* __restrict__ out, int N)
{
  __shared__ u16 As[128][72];
  __shared__ u16 Bs[128][72];
  const int t = threadIdx.x;
  const int l = t & 63, w = t >> 6;
  const int wr = w >> 1, wc = w & 1;
  const int m0 = blockIdx.x * 128, n0 = blockIdx.y * 128;
  const int sr = t >> 1, sc = (t & 1) * 32;
  const int lr = l & 15, lk = (l >> 4) * 8;
  f32x4 acc[4][4] = {};

  for (int kt = 0; kt < 4; ++kt){
    const int k0 = kt * 64;
    __syncthreads();
    {
      const float4* ap = reinterpret_cast<const float4*>(
          A + (size_t)(m0 + sr) * CDIM + k0 + sc);
      #pragma unroll
      for (int i = 0; i < 4; ++i){
        float4 f0 = ap[2 * i], f1 = ap[2 * i + 1];
        BF8 p; cvt8(f0, f1, p);
        *reinterpret_cast<uint4*>(&As[sr][sc + 8 * i]) = p.q;
      }
      const uint4* bp = reinterpret_cast<const uint4*>(
          WT + (size_t)(n0 + sr) * CDIM + k0 + sc);
      #pragma unroll
      for (int i = 0; i < 4; ++i)
        *reinterpret_cast<uint4*>(&Bs[sr][sc + 8 * i]) = bp[i];
    }
    __syncthreads();
    #pragma unroll
    for (int kk = 0; kk < 64; kk += 32){
      bf16x8 af[4], bfr[4];
      #pragma unroll
      for (int m = 0; m < 4; ++m)
        af[m] = *reinterpret_cast<const bf16x8*>(&As[wr * 64 + m * 16 + lr][kk + lk]);
      #pragma unroll
      for (int n = 0; n < 4; ++n)
        bfr[n] = *reinterpret_cast<const bf16x8*>(&Bs[wc * 64 + n * 16 + lr][kk + lk]);
      #pragma unroll
      for (int m = 0; m < 4; ++m)
        #pragma unroll
        for (int n = 0; n < 4; ++n)
          acc[m][n] = __builtin_amdgcn_mfma_f32_16x16x32_bf16(af[m], bfr[n], acc[m][n], 0, 0, 0);
    }
  }

  const int rj = (l >> 4) * 4;
  #pragma unroll
  for (int m = 0; m < 4; ++m){
    #pragma unroll
    for (int n = 0; n < 4; ++n){
      const int gcol = n0 + wc * 64 + n * 16 + lr;
      if (gcol < N){
        #pragma unroll
        for (int j = 0; j < 4; ++j){
          const int grow = m0 + wr * 64 + m * 16 + rj + j;
          const size_t o = (size_t)grow * N + gcol;
          float v = acc[m][n][j];
          if (BIAS) v += bias[gcol];
          if (RES)  v += res[o];
          if (RELU) v = fmaxf(v, 0.f);
          out[o] = v;
        }
      }
    }
  }
}

// ---------------------------------------------------------------------------
// Attention: one block per (b,h). 4 waves, each wave owns 16 q-rows per
// 64-row chunk. K fragments in registers, V transposed in LDS, P in LDS bf16.
// scale = C^-0.5 = 1/16 (reference scales by n_embed^-0.5).
// ---------------------------------------------------------------------------
__global__ __launch_bounds__(256) void attn_k(
    const float* __restrict__ Qg, const float* __restrict__ Kg,
    const float* __restrict__ Vg, float* __restrict__ Og)
{
  __shared__ u16 Vt[32][264];   // V^T: [d][t_k]
  __shared__ u16 Ps[64][264];   // P for current 64-row chunk: [q_local][t_k]
  const int bh = blockIdx.x;
  const size_t base = (size_t)(bh >> 3) * (256 * CDIM) + (size_t)(bh & 7) * 32;
  const int t = threadIdx.x, l = t & 63, w = t >> 6;
  const int lr = l & 15, lk = (l >> 4) * 8;

  // stage V transposed (thread t handles k-row t)
  {
    const float4* vp = reinterpret_cast<const float4*>(Vg + base + (size_t)t * CDIM);
    #pragma unroll
    for (int i = 0; i < 8; ++i){
      float4 f = vp[i];
      Vt[4 * i + 0][t] = f2bf(f.x);
      Vt[4 * i + 1][t] = f2bf(f.y);
      Vt[4 * i + 2][t] = f2bf(f.z);
      Vt[4 * i + 3][t] = f2bf(f.w);
    }
  }
  // K fragments in registers: kf[n] covers t_k rows n*16..n*16+15
  bf16x8 kf[16];
  #pragma unroll
  for (int n = 0; n < 16; ++n){
    const float4* kp = reinterpret_cast<const float4*>(
        Kg + base + (size_t)(n * 16 + lr) * CDIM + lk);
    BF8 p; cvt8(kp[0], kp[1], p);
    kf[n] = p.v;
  }
  __syncthreads();

  for (int c = 0; c < 4; ++c){
    const int rowb = c * 64 + w * 16;
    // Q fragment straight from global
    const float4* qp = reinterpret_cast<const float4*>(
        Qg + base + (size_t)(rowb + lr) * CDIM + lk);
    BF8 qa; cvt8(qp[0], qp[1], qa);

    f32x4 s[16];
    #pragma unroll
    for (int n = 0; n < 16; ++n){
      f32x4 z = {};
      s[n] = __builtin_amdgcn_mfma_f32_16x16x32_bf16(qa.v, kf[n], z, 0, 0, 0);
    }

    float inv[4];
    const int prow = w * 16 + (l >> 4) * 4;
    #pragma unroll
    for (int j = 0; j < 4; ++j){
      const int qrow = rowb + (l >> 4) * 4 + j;   // global t_q (0..255)
      float sv[16]; float mx = -1e30f;
      #pragma unroll
      for (int n = 0; n < 16; ++n){
        float vv = s[n][j] * 0.0625f;
        sv[n] = ((n * 16 + lr) <= qrow) ? vv : -1e30f;
        mx = fmaxf(mx, sv[n]);
      }
      #pragma unroll
      for (int o = 1; o < 16; o <<= 1) mx = fmaxf(mx, __shfl_xor(mx, o));
      float sum = 0.f;
      #pragma unroll
      for (int n = 0; n < 16; ++n){
        float p = __expf(sv[n] - mx);
        sum += p;
        Ps[prow + j][n * 16 + lr] = f2bf(p);
      }
      #pragma unroll
      for (int o = 1; o < 16; o <<= 1) sum += __shfl_xor(sum, o);
      inv[j] = 1.f / sum;
    }
    __syncthreads();

    f32x4 o0 = {}, o1 = {};
    #pragma unroll
    for (int kc = 0; kc < 8; ++kc){
      bf16x8 pa = *reinterpret_cast<const bf16x8*>(&Ps[w * 16 + lr][kc * 32 + lk]);
      bf16x8 v0 = *reinterpret_cast<const bf16x8*>(&Vt[lr][kc * 32 + lk]);
      bf16x8 v1 = *reinterpret_cast<const bf16x8*>(&Vt[16 + lr][kc * 32 + lk]);
      o0 = __builtin_amdgcn_mfma_f32_16x16x32_bf16(pa, v0, o0, 0, 0, 0);
      o1 = __builtin_amdgcn_mfma_f32_16x16x32_bf16(pa, v1, o1, 0, 0, 0);
    }
    #pragma unroll
    for (int j = 0; j < 4; ++j){
      const int qrow = rowb + (l >> 4) * 4 + j;
      float* op = Og + base + (size_t)qrow * CDIM;
      op[lr]      = o0[j] * inv[j];
      op[16 + lr] = o1[j] * inv[j];
    }
    __syncthreads();
  }
}

// ---------------------------------------------------------------------------
// LayerNorm over C=256: one block per row.
// ---------------------------------------------------------------------------
__global__ __launch_bounds__(256) void ln_k(
    const float* __restrict__ in, const float* __restrict__ w,
    const float* __restrict__ b, float* __restrict__ out)
{
  __shared__ float rs[4], rq[4];
  const int r = blockIdx.x, c = threadIdx.x;
  const float v = in[(size_t)r * CDIM + c];
  float s = v, q = v * v;
  #pragma unroll
  for (int o = 32; o; o >>= 1){ s += __shfl_xor(s, o); q += __shfl_xor(q, o); }
  if ((c & 63) == 0){ rs[c >> 6] = s; rq[c >> 6] = q; }
  __syncthreads();
  s = rs[0] + rs[1] + rs[2] + rs[3];
  q = rq[0] + rq[1] + rq[2] + rq[3];
  const float mean = s * (1.f / 256.f);
  const float var  = q * (1.f / 256.f) - mean * mean;
  const float rstd = rsqrtf(var + 1e-5f);
  out[(size_t)r * CDIM + c] = (v - mean) * rstd * w[c] + b[c];
}

// ---------------------------------------------------------------------------
// Per-row NLL: one wave per row (V=96). nll[r] = lse(logits[r]) - logits[r][tgt]
// ---------------------------------------------------------------------------
__global__ __launch_bounds__(256) void nll_k(
    const float* __restrict__ logits, const int* __restrict__ target,
    float* __restrict__ nll)
{
  const int w = threadIdx.x >> 6, l = threadIdx.x & 63;
  const int r = blockIdx.x * 4 + w;
  const float* row = logits + (size_t)r * 96;
  float v0 = row[l];
  float v1 = (l < 32) ? row[64 + l] : -1e30f;
  float m = fmaxf(v0, v1);
  #pragma unroll
  for (int o = 32; o; o >>= 1) m = fmaxf(m, __shfl_xor(m, o));
  float s = __expf(v0 - m) + ((l < 32) ? __expf(v1 - m) : 0.f);
  #pragma unroll
  for (int o = 32; o; o >>= 1) s += __shfl_xor(s, o);
  if (l == 0) nll[r] = logf(s) + m - row[target[r]];
}

__global__ __launch_bounds__(256) void loss_k(
    const float* __restrict__ nll, float* __restrict__ out)
{
  __shared__ float rs[4];
  float s = 0.f;
  for (int i = threadIdx.x; i < NT; i += 256) s += nll[i];
  #pragma unroll
  for (int o = 32; o; o >>= 1) s += __shfl_xor(s, o);
  if ((threadIdx.x & 63) == 0) rs[threadIdx.x >> 6] = s;
  __syncthreads();
  if (threadIdx.x == 0) out[0] = (rs[0] + rs[1] + rs[2] + rs[3]) * (1.f / 16384.f);
}

// ---------------------------------------------------------------------------
extern "C" void kernel_launch(void* const* d_in, const int* in_sizes, int n_in,
                              void* d_out, int out_size, void* d_ws, size_t ws_size,
                              hipStream_t stream)
{
  const int*   idx    = (const int*)  d_in[0];
  const int*   target = (const int*)  d_in[1];
  const float* tok    = (const float*)d_in[2];
  const float* pos    = (const float*)d_in[3];
  const float* Wq     = (const float*)d_in[4];
  const float* Wk     = (const float*)d_in[5];
  const float* Wv     = (const float*)d_in[6];
  const float* Wo     = (const float*)d_in[7];
  const float* bo     = (const float*)d_in[8];
  const float* W1     = (const float*)d_in[9];
  const float* b1     = (const float*)d_in[10];
  const float* W2     = (const float*)d_in[11];
  const float* b2     = (const float*)d_in[12];
  const float* ln1w   = (const float*)d_in[13];
  const float* ln1b   = (const float*)d_in[14];
  const float* ln2w   = (const float*)d_in[15];
  const float* ln2b   = (const float*)d_in[16];
  const float* lnfw   = (const float*)d_in[17];
  const float* lnfb   = (const float*)d_in[18];
  const float* Wlm    = (const float*)d_in[19];
  const float* blm    = (const float*)d_in[20];
  float* out = (float*)d_out;

  char* ws = (char*)d_ws;
  const size_t BUF = (size_t)NT * CDIM * sizeof(float);   // 16 MiB
  float* X  = (float*)(ws);
  float* Qb = (float*)(ws + BUF);         // also attention output (aliased)
  float* Kb = (float*)(ws + 2 * BUF);     // also MLP hidden h
  float* Vb = (float*)(ws + 3 * BUF);     // also pre-LN scratch y
  u16*   WT = (u16*)  (ws + 4 * BUF);     // 37 * 65536 bf16
  float* nl = (float*)(ws + 4 * BUF + (size_t)37 * 65536 * 2);

  wconv_k<<<dim3(4, 4, 37), 256, 0, stream>>>(Wq, Wk, Wv, Wo, W1, W2, Wlm, WT);
  embed_k<<<NT, 256, 0, stream>>>(idx, tok, pos, X);

  for (int l = 0; l < LAYERS; ++l){
    const u16* wq = WT + (size_t)(0 * 6 + l) * 65536;
    const u16* wk = WT + (size_t)(1 * 6 + l) * 65536;
    const u16* wv = WT + (size_t)(2 * 6 + l) * 65536;
    const u16* wo = WT + (size_t)(3 * 6 + l) * 65536;
    const u16* w1 = WT + (size_t)(4 * 6 + l) * 65536;
    const u16* w2 = WT + (size_t)(5 * 6 + l) * 65536;

    gemm_k<false, false, false><<<dim3(128, 2), 256, 0, stream>>>(X, wq, nullptr, nullptr, Qb, 256);
    gemm_k<false, false, false><<<dim3(128, 2), 256, 0, stream>>>(X, wk, nullptr, nullptr, Kb, 256);
    gemm_k<false, false, false><<<dim3(128, 2), 256, 0, stream>>>(X, wv, nullptr, nullptr, Vb, 256);
    attn_k<<<512, 256, 0, stream>>>(Qb, Kb, Vb, Qb);
    gemm_k<true, false, true><<<dim3(128, 2), 256, 0, stream>>>(Qb, wo, bo + l * 256, X, Vb, 256);
    ln_k<<<NT, 256, 0, stream>>>(Vb, ln1w + l * 256, ln1b + l * 256, X);
    gemm_k<true, true, false><<<dim3(128, 2), 256, 0, stream>>>(X, w1, b1 + l * 256, nullptr, Kb, 256);
    gemm_k<true, false, true><<<dim3(128, 2), 256, 0, stream>>>(Kb, w2, b2 + l * 256, X, Vb, 256);
    ln_k<<<NT, 256, 0, stream>>>(Vb, ln2w + l * 256, ln2b + l * 256, X);
  }

  ln_k<<<NT, 256, 0, stream>>>(X, lnfw, lnfb, Vb);
  gemm_k<true, false, false><<<dim3(128, 1), 256, 0, stream>>>(Vb, WT + (size_t)36 * 65536, blm, nullptr, out, 96);
  nll_k<<<NT / 4, 256, 0, stream>>>(out, target, nl);
  loss_k<<<1, 256, 0, stream>>>(nl, out + (size_t)NT * 96);
}

// Round 2
// 665.114 us; speedup vs baseline: 1.6112x; 1.6112x over previous
//
#include <hip/hip_runtime.h>

typedef unsigned short u16;

#define NT   16384   // B*T
#define CDIM 256
#define LAYERS 6

using bf16x8 = __attribute__((ext_vector_type(8))) __bf16;
using f32x4  = __attribute__((ext_vector_type(4))) float;

__device__ __forceinline__ u16 f2bf(float x){
  unsigned u = __float_as_uint(x);
  u += 0x7fffu + ((u >> 16) & 1u);
  return (u16)(u >> 16);
}

// async global->LDS, 16 bytes per lane (global_load_lds_dwordx4)
__device__ __forceinline__ void gll16(const u16* g, u16* l){
  __builtin_amdgcn_global_load_lds(
      (const __attribute__((address_space(1))) unsigned int*)g,
      (__attribute__((address_space(3))) unsigned int*)l, 16, 0, 0);
}

// ---------------------------------------------------------------------------
// Weight transpose+convert: fp32 [K=256][N] -> bf16 [Npad][256] (row n = W[:,n])
// z 0..17:  QKV  (layer l = z/3, which = z%3) -> WT + l*196608 + which*65536
// z 18..35: Wo/W1/W2 (j=(z-18)/6, l=(z-18)%6) -> WT + 1179648 + (j*6+l)*65536
// z 36:     Wlm [256][96] -> [128][256] at WT + 2359296 (rows 96..127 zero)
// ---------------------------------------------------------------------------
__global__ __launch_bounds__(256) void wconv_k(
    const float* __restrict__ Wq, const float* __restrict__ Wk,
    const float* __restrict__ Wv, const float* __restrict__ Wo,
    const float* __restrict__ W1, const float* __restrict__ W2,
    const float* __restrict__ Wlm, u16* __restrict__ WT)
{
  __shared__ float tile[64][65];
  const int z = blockIdx.z;
  const float* src; u16* dst; int N = 256, Npad = 256;
  if (z < 18){
    const int l = z / 3, which = z % 3;
    const float* a[3] = {Wq, Wk, Wv};
    src = a[which] + (size_t)l * 65536;
    dst = WT + (size_t)l * 196608 + (size_t)which * 65536;
  } else if (z < 36){
    const int i = z - 18, j = i / 6, l = i % 6;
    const float* a[3] = {Wo, W1, W2};
    src = a[j] + (size_t)l * 65536;
    dst = WT + 1179648 + (size_t)(j * 6 + l) * 65536;
  } else {
    src = Wlm; dst = WT + 2359296; N = 96; Npad = 128;
  }
  const int n0 = blockIdx.y * 64, k0 = blockIdx.x * 64;
  if (n0 >= Npad) return;
  const int c = threadIdx.x & 63, r0 = threadIdx.x >> 6;
  #pragma unroll
  for (int i = 0; i < 16; ++i){
    const int r = r0 + i * 4;
    tile[r][c] = (n0 + c < N) ? src[(size_t)(k0 + r) * N + n0 + c] : 0.f;
  }
  __syncthreads();
  #pragma unroll
  for (int i = 0; i < 16; ++i){
    const int cp = r0 + i * 4;
    dst[(size_t)(n0 + cp) * CDIM + k0 + c] = f2bf(tile[c][cp]);
  }
}

// ---------------------------------------------------------------------------
// Embedding: wave per row. X fp32 + Xb bf16.
// ---------------------------------------------------------------------------
__global__ __launch_bounds__(256) void embed_k(
    const int* __restrict__ idx, const float* __restrict__ tok,
    const float* __restrict__ pos, float* __restrict__ X, u16* __restrict__ Xb)
{
  const int w = threadIdx.x >> 6, l = threadIdx.x & 63;
  const int r = blockIdx.x * 4 + w;
  const int id = idx[r];
  float4 tv = *reinterpret_cast<const float4*>(tok + (size_t)id * CDIM + l * 4);
  float4 pv = *reinterpret_cast<const float4*>(pos + (size_t)(r & 255) * CDIM + l * 4);
  float4 y = {tv.x + pv.x, tv.y + pv.y, tv.z + pv.z, tv.w + pv.w};
  *reinterpret_cast<float4*>(X + (size_t)r * CDIM + l * 4) = y;
  union { u16 u[4]; uint2 q; } p;
  p.u[0] = f2bf(y.x); p.u[1] = f2bf(y.y); p.u[2] = f2bf(y.z); p.u[3] = f2bf(y.w);
  *reinterpret_cast<uint2*>(Xb + (size_t)r * CDIM + l * 4) = p.q;
}

// ---------------------------------------------------------------------------
// GEMM: out[M,N] = A[M,256](bf16) * W, WT bf16 [Npad][256]. TMx128 tile, BK=64,
// 4 waves (2x2), global_load_lds staging, mfma_f32_16x16x32_bf16.
// Epilogue: +bias, +res(fp32), relu; out fp32 or bf16.
// ---------------------------------------------------------------------------
template<int TM, bool BIAS, bool RELU, bool RES, bool OBF>
__global__ __launch_bounds__(256) void gemm_k(
    const u16* __restrict__ A, const u16* __restrict__ WT,
    const float* __restrict__ bias, const float* __restrict__ res,
    void* __restrict__ outp, int N, int ldo)
{
  __shared__ u16 As[TM * 64];
  __shared__ u16 Bs[128 * 64];
  const int t = threadIdx.x, l = t & 63, w = t >> 6;
  const int wr = w >> 1, wc = w & 1;
  const int m0 = blockIdx.x * TM, n0 = blockIdx.y * 128;
  const int lr = l & 15, lk = (l >> 4) * 8;
  const int row = t >> 3, c8 = (t & 7) * 8;
  constexpr int MR = TM / 32;
  f32x4 acc[MR][4] = {};

  for (int kt = 0; kt < 4; ++kt){
    const int k0 = kt * 64;
    if (kt) __syncthreads();
    #pragma unroll
    for (int i = 0; i < MR; ++i)
      gll16(A + (size_t)(m0 + row + 32 * i) * CDIM + k0 + c8, As + t * 8 + i * 2048);
    #pragma unroll
    for (int i = 0; i < 4; ++i)
      gll16(WT + (size_t)(n0 + row + 32 * i) * CDIM + k0 + c8, Bs + t * 8 + i * 2048);
    __syncthreads();
    #pragma unroll
    for (int kk = 0; kk < 64; kk += 32){
      bf16x8 af[MR], bfr[4];
      #pragma unroll
      for (int m = 0; m < MR; ++m)
        af[m] = *reinterpret_cast<const bf16x8*>(&As[(wr * (TM / 2) + m * 16 + lr) * 64 + kk + lk]);
      #pragma unroll
      for (int n = 0; n < 4; ++n)
        bfr[n] = *reinterpret_cast<const bf16x8*>(&Bs[(wc * 64 + n * 16 + lr) * 64 + kk + lk]);
      #pragma unroll
      for (int m = 0; m < MR; ++m)
        #pragma unroll
        for (int n = 0; n < 4; ++n)
          acc[m][n] = __builtin_amdgcn_mfma_f32_16x16x32_bf16(af[m], bfr[n], acc[m][n], 0, 0, 0);
    }
  }

  const int rj = (l >> 4) * 4;
  #pragma unroll
  for (int m = 0; m < MR; ++m){
    #pragma unroll
    for (int n = 0; n < 4; ++n){
      const int gcol = n0 + wc * 64 + n * 16 + lr;
      if (gcol < N){
        #pragma unroll
        for (int j = 0; j < 4; ++j){
          const int grow = m0 + wr * (TM / 2) + m * 16 + rj + j;
          const size_t o = (size_t)grow * ldo + gcol;
          float v = acc[m][n][j];
          if (BIAS) v += bias[gcol];
          if (RES)  v += res[o];
          if (RELU) v = fmaxf(v, 0.f);
          if (OBF) ((u16*)outp)[o] = f2bf(v);
          else     ((float*)outp)[o] = v;
        }
      }
    }
  }
}

// ---------------------------------------------------------------------------
// Attention: block per (b,h). QKV bf16 [NT][768]: Q cols 0..255, K 256..511,
// V 512..767 (col = h*32+d). O bf16 [NT][256]. scale = 1/16 (C^-0.5).
// ---------------------------------------------------------------------------
__global__ __launch_bounds__(256) void attn_k(
    const u16* __restrict__ QKV, u16* __restrict__ O)
{
  __shared__ u16 Vt[32][264];   // V^T [d][t_k]
  __shared__ u16 Ps[64][264];   // P chunk [q_local][t_k]
  const int bh = blockIdx.x, b = bh >> 3, h = bh & 7;
  const size_t rbase = (size_t)b * 256 * 768;
  const int qc = h * 32, kc = 256 + h * 32, vc = 512 + h * 32;
  const int t = threadIdx.x, l = t & 63, w = t >> 6;
  const int lr = l & 15, lk = (l >> 4) * 8;

  // stage V transposed (thread t = k-row t)
  {
    const uint4* vp = reinterpret_cast<const uint4*>(QKV + rbase + (size_t)t * 768 + vc);
    #pragma unroll
    for (int i = 0; i < 4; ++i){
      union { uint4 q; u16 u[8]; } p; p.q = vp[i];
      #pragma unroll
      for (int j = 0; j < 8; ++j) Vt[i * 8 + j][t] = p.u[j];
    }
  }
  // K fragments in registers
  bf16x8 kf[16];
  #pragma unroll
  for (int n = 0; n < 16; ++n)
    kf[n] = *reinterpret_cast<const bf16x8*>(QKV + rbase + (size_t)(n * 16 + lr) * 768 + kc + lk);
  __syncthreads();

  for (int c = 0; c < 4; ++c){
    const int rowb = c * 64 + w * 16;
    bf16x8 qa = *reinterpret_cast<const bf16x8*>(QKV + rbase + (size_t)(rowb + lr) * 768 + qc + lk);

    f32x4 s[16];
    #pragma unroll
    for (int n = 0; n < 16; ++n){
      f32x4 z = {};
      s[n] = __builtin_amdgcn_mfma_f32_16x16x32_bf16(qa, kf[n], z, 0, 0, 0);
    }

    float inv[4];
    const int prow = w * 16 + (l >> 4) * 4;
    #pragma unroll
    for (int j = 0; j < 4; ++j){
      const int qrow = rowb + (l >> 4) * 4 + j;
      float sv[16]; float mx = -1e30f;
      #pragma unroll
      for (int n = 0; n < 16; ++n){
        float vv = s[n][j] * 0.0625f;
        sv[n] = ((n * 16 + lr) <= qrow) ? vv : -1e30f;
        mx = fmaxf(mx, sv[n]);
      }
      #pragma unroll
      for (int o = 1; o < 16; o <<= 1) mx = fmaxf(mx, __shfl_xor(mx, o));
      float sum = 0.f;
      #pragma unroll
      for (int n = 0; n < 16; ++n){
        float p = __expf(sv[n] - mx);
        sum += p;
        Ps[prow + j][n * 16 + lr] = f2bf(p);
      }
      #pragma unroll
      for (int o = 1; o < 16; o <<= 1) sum += __shfl_xor(sum, o);
      inv[j] = 1.f / sum;
    }
    __syncthreads();

    f32x4 o0 = {}, o1 = {};
    #pragma unroll
    for (int kc2 = 0; kc2 < 8; ++kc2){
      bf16x8 pa = *reinterpret_cast<const bf16x8*>(&Ps[w * 16 + lr][kc2 * 32 + lk]);
      bf16x8 v0 = *reinterpret_cast<const bf16x8*>(&Vt[lr][kc2 * 32 + lk]);
      bf16x8 v1 = *reinterpret_cast<const bf16x8*>(&Vt[16 + lr][kc2 * 32 + lk]);
      o0 = __builtin_amdgcn_mfma_f32_16x16x32_bf16(pa, v0, o0, 0, 0, 0);
      o1 = __builtin_amdgcn_mfma_f32_16x16x32_bf16(pa, v1, o1, 0, 0, 0);
    }
    #pragma unroll
    for (int j = 0; j < 4; ++j){
      const int qrow = rowb + (l >> 4) * 4 + j;
      u16* op = O + (size_t)(b * 256 + qrow) * CDIM + h * 32;
      op[lr]      = f2bf(o0[j] * inv[j]);
      op[16 + lr] = f2bf(o1[j] * inv[j]);
    }
    __syncthreads();
  }
}

// ---------------------------------------------------------------------------
// LayerNorm, wave per row: fp32 in -> fp32 X (optional) + bf16 Xb.
// ---------------------------------------------------------------------------
template<bool WX>
__global__ __launch_bounds__(256) void ln_k(
    const float* __restrict__ in, const float* __restrict__ w,
    const float* __restrict__ b, float* __restrict__ X, u16* __restrict__ Xb)
{
  const int wv = threadIdx.x >> 6, l = threadIdx.x & 63;
  const int r = blockIdx.x * 4 + wv;
  float4 v = *reinterpret_cast<const float4*>(in + (size_t)r * CDIM + l * 4);
  float s = v.x + v.y + v.z + v.w;
  float q = v.x * v.x + v.y * v.y + v.z * v.z + v.w * v.w;
  #pragma unroll
  for (int o = 32; o; o >>= 1){ s += __shfl_xor(s, o); q += __shfl_xor(q, o); }
  const float mean = s * (1.f / 256.f);
  const float var  = q * (1.f / 256.f) - mean * mean;
  const float rstd = rsqrtf(var + 1e-5f);
  float4 w4 = *reinterpret_cast<const float4*>(w + l * 4);
  float4 b4 = *reinterpret_cast<const float4*>(b + l * 4);
  float4 y;
  y.x = (v.x - mean) * rstd * w4.x + b4.x;
  y.y = (v.y - mean) * rstd * w4.y + b4.y;
  y.z = (v.z - mean) * rstd * w4.z + b4.z;
  y.w = (v.w - mean) * rstd * w4.w + b4.w;
  if (WX) *reinterpret_cast<float4*>(X + (size_t)r * CDIM + l * 4) = y;
  union { u16 u[4]; uint2 q2; } p;
  p.u[0] = f2bf(y.x); p.u[1] = f2bf(y.y); p.u[2] = f2bf(y.z); p.u[3] = f2bf(y.w);
  *reinterpret_cast<uint2*>(Xb + (size_t)r * CDIM + l * 4) = p.q2;
}

// ---------------------------------------------------------------------------
// NLL + loss
// ---------------------------------------------------------------------------
__global__ __launch_bounds__(256) void nll_k(
    const float* __restrict__ logits, const int* __restrict__ target,
    float* __restrict__ nll)
{
  const int w = threadIdx.x >> 6, l = threadIdx.x & 63;
  const int r = blockIdx.x * 4 + w;
  const float* row = logits + (size_t)r * 96;
  float v0 = row[l];
  float v1 = (l < 32) ? row[64 + l] : -1e30f;
  float m = fmaxf(v0, v1);
  #pragma unroll
  for (int o = 32; o; o >>= 1) m = fmaxf(m, __shfl_xor(m, o));
  float s = __expf(v0 - m) + ((l < 32) ? __expf(v1 - m) : 0.f);
  #pragma unroll
  for (int o = 32; o; o >>= 1) s += __shfl_xor(s, o);
  if (l == 0) nll[r] = logf(s) + m - row[target[r]];
}

__global__ __launch_bounds__(256) void loss_k(
    const float* __restrict__ nll, float* __restrict__ out)
{
  __shared__ float rs[4];
  float s = 0.f;
  for (int i = threadIdx.x; i < NT; i += 256) s += nll[i];
  #pragma unroll
  for (int o = 32; o; o >>= 1) s += __shfl_xor(s, o);
  if ((threadIdx.x & 63) == 0) rs[threadIdx.x >> 6] = s;
  __syncthreads();
  if (threadIdx.x == 0) out[0] = (rs[0] + rs[1] + rs[2] + rs[3]) * (1.f / 16384.f);
}

// ---------------------------------------------------------------------------
extern "C" void kernel_launch(void* const* d_in, const int* in_sizes, int n_in,
                              void* d_out, int out_size, void* d_ws, size_t ws_size,
                              hipStream_t stream)
{
  const int*   idx    = (const int*)  d_in[0];
  const int*   target = (const int*)  d_in[1];
  const float* tok    = (const float*)d_in[2];
  const float* pos    = (const float*)d_in[3];
  const float* Wq     = (const float*)d_in[4];
  const float* Wk     = (const float*)d_in[5];
  const float* Wv     = (const float*)d_in[6];
  const float* Wo     = (const float*)d_in[7];
  const float* bo     = (const float*)d_in[8];
  const float* W1     = (const float*)d_in[9];
  const float* b1     = (const float*)d_in[10];
  const float* W2     = (const float*)d_in[11];
  const float* b2     = (const float*)d_in[12];
  const float* ln1w   = (const float*)d_in[13];
  const float* ln1b   = (const float*)d_in[14];
  const float* ln2w   = (const float*)d_in[15];
  const float* ln2b   = (const float*)d_in[16];
  const float* lnfw   = (const float*)d_in[17];
  const float* lnfb   = (const float*)d_in[18];
  const float* Wlm    = (const float*)d_in[19];
  const float* blm    = (const float*)d_in[20];
  float* out = (float*)d_out;

  char* ws = (char*)d_ws;
  float* X   = (float*)(ws);                          // 16 MiB residual fp32
  float* y   = (float*)(ws + (16u << 20));            // 16 MiB pre-LN fp32
  u16*   Xb  = (u16*)  (ws + (32u << 20));            // 8 MiB bf16 GEMM input
  u16*   QKV = (u16*)  (ws + (40u << 20));            // 24 MiB bf16 [NT][768]
  u16*   O   = (u16*)  (ws + (64u << 20));            // 8 MiB bf16 attn out
  u16*   hB  = (u16*)  (ws + (72u << 20));            // 8 MiB bf16 MLP hidden
  u16*   WT  = (u16*)  (ws + (80u << 20));            // ~4.8 MiB bf16 weights
  float* nl  = (float*)(ws + (88u << 20));            // 64 KiB

  wconv_k<<<dim3(4, 4, 37), 256, 0, stream>>>(Wq, Wk, Wv, Wo, W1, W2, Wlm, WT);
  embed_k<<<NT / 4, 256, 0, stream>>>(idx, tok, pos, X, Xb);

  for (int l = 0; l < LAYERS; ++l){
    const u16* wqkv = WT + (size_t)l * 196608;
    const u16* wo   = WT + 1179648 + (size_t)(0 * 6 + l) * 65536;
    const u16* w1   = WT + 1179648 + (size_t)(1 * 6 + l) * 65536;
    const u16* w2   = WT + 1179648 + (size_t)(2 * 6 + l) * 65536;

    gemm_k<128, false, false, false, true><<<dim3(128, 6), 256, 0, stream>>>(
        Xb, wqkv, nullptr, nullptr, QKV, 768, 768);
    attn_k<<<512, 256, 0, stream>>>(QKV, O);
    gemm_k<64, true, false, true, false><<<dim3(256, 2), 256, 0, stream>>>(
        O, wo, bo + l * 256, X, y, 256, 256);
    ln_k<true><<<NT / 4, 256, 0, stream>>>(y, ln1w + l * 256, ln1b + l * 256, X, Xb);
    gemm_k<64, true, true, false, true><<<dim3(256, 2), 256, 0, stream>>>(
        Xb, w1, b1 + l * 256, nullptr, hB, 256, 256);
    gemm_k<64, true, false, true, false><<<dim3(256, 2), 256, 0, stream>>>(
        hB, w2, b2 + l * 256, X, y, 256, 256);
    ln_k<true><<<NT / 4, 256, 0, stream>>>(y, ln2w + l * 256, ln2b + l * 256, X, Xb);
  }

  ln_k<false><<<NT / 4, 256, 0, stream>>>(X, lnfw, lnfb, nullptr, Xb);
  gemm_k<64, true, false, false, false><<<dim3(256, 1), 256, 0, stream>>>(
      Xb, WT + 2359296, blm, nullptr, out, 96, 96);
  nll_k<<<NT / 4, 256, 0, stream>>>(out, target, nl);
  loss_k<<<1, 256, 0, stream>>>(nl, out + (size_t)NT * 96);
}